// Round 3
// baseline (2095.761 us; speedup 1.0000x reference)
//
#include <hip/hip_runtime.h>
#include <math.h>

#define N_NODES_ 50000
#define N_EDGES_ 1000000
#define HID 128
#define NG 50
#define NF 128
#define NCOL 4
#define CHUNK 625
#define NCHUNK 80              // 80*625 = 50000 dst keys

typedef short s16x8 __attribute__((ext_vector_type(8)));
typedef float f32x4 __attribute__((ext_vector_type(4)));
typedef float f32x4u __attribute__((ext_vector_type(4), aligned(4)));
typedef float f32x2u __attribute__((ext_vector_type(2), aligned(4)));

__device__ __forceinline__ float sspf(float v) {
    float r = __logf(1.f + __expf(v)) - 0.69314718055994531f;
    return (v > 15.f) ? (v - 0.69314718055994531f) : r;
}

__device__ __forceinline__ unsigned int f2b(float f) {  // f32 -> bf16 (RNE), low 16
    unsigned int u = __float_as_uint(f);
    return (u + 0x7fffu + ((u >> 16) & 1u)) >> 16;
}

// ---------------- histogram over dst ----------------
__global__ __launch_bounds__(256) void hist_kernel(const int* __restrict__ edge_index,
                                                   int* __restrict__ hist) {
    int e = blockIdx.x * 256 + threadIdx.x;
    if (e < N_EDGES_) atomicAdd(&hist[edge_index[N_EDGES_ + e]], 1);
}

// ---------------- per-chunk exclusive scan (in place) ----------------
__global__ __launch_bounds__(256) void scan1_kernel(int* __restrict__ hist,
                                                    int* __restrict__ csum) {
    __shared__ int s[CHUNK];
    int b = blockIdx.x;                  // 0..79
    int gofs = b * CHUNK;
    for (int i = threadIdx.x; i < CHUNK; i += 256) s[i] = hist[gofs + i];
    __syncthreads();
    if (threadIdx.x == 0) {
        int run = 0;
        for (int i = 0; i < CHUNK; ++i) { int t = s[i]; s[i] = run; run += t; }
        csum[b] = run;
    }
    __syncthreads();
    for (int i = threadIdx.x; i < CHUNK; i += 256) hist[gofs + i] = s[i];
}

__global__ __launch_bounds__(64) void scan2_kernel(const int* __restrict__ csum,
                                                   int* __restrict__ cbase) {
    if (threadIdx.x == 0) {
        int run = 0;
        for (int j = 0; j < NCHUNK; ++j) { cbase[j] = run; run += csum[j]; }
    }
}

__global__ __launch_bounds__(256) void scan3_kernel(int* __restrict__ hist,
                                                    const int* __restrict__ cbase) {
    int b = blockIdx.x;
    int add = cbase[b];
    int gofs = b * CHUNK;
    for (int i = threadIdx.x; i < CHUNK; i += 256) hist[gofs + i] += add;
}

// ---------------- scatter into dst-sorted order ----------------
__global__ __launch_bounds__(256) void scatter_kernel(const int* __restrict__ edge_index,
                                                      int* __restrict__ base,
                                                      int* __restrict__ eid_s) {
    int e = blockIdx.x * 256 + threadIdx.x;
    if (e < N_EDGES_) {
        int d = edge_index[N_EDGES_ + e];
        int r = atomicAdd(&base[d], 1);
        eid_s[r] = e;
    }
}

// ---------------- convert MLP weights to bf16 (zero-padded K for m1) ----------------
__global__ __launch_bounds__(256) void wconv_kernel(const float* __restrict__ m1w,
                                                    const float* __restrict__ m2w,
                                                    unsigned short* __restrict__ m1b16,
                                                    unsigned short* __restrict__ m2b16) {
    int idx = blockIdx.x * 256 + threadIdx.x;
    if (idx < NCOL * NF * 64) {
        int c = idx / (NF * 64);
        int rem = idx % (NF * 64);
        int n = rem / 64, k = rem % 64;
        float v = (k < NG) ? m1w[(c * NF + n) * NG + k] : 0.f;
        m1b16[idx] = (unsigned short)f2b(v);
    } else if (idx < NCOL * NF * 64 + NCOL * NF * NF) {
        int j = idx - NCOL * NF * 64;
        m2b16[j] = (unsigned short)f2b(m2w[j]);
    }
}

// ---------------- fused edge pass: barrier-free, wave-autonomous ----------------
// 64 dst-sorted edges per block (16 per wave). 4 color passes over shared MFMA tiles.
// In-register segmented reduction over dst runs; tail lanes emit native f32 atomics.
__global__ __launch_bounds__(256, 4) void passA_kernel(
    const int* __restrict__ edge_index, const float* __restrict__ edge_weight,
    const float* __restrict__ edge_attr, const int* __restrict__ colors,
    const unsigned short* __restrict__ m1b16, const unsigned short* __restrict__ m2b16,
    const float* __restrict__ m1bias, const float* __restrict__ m2bias,
    const float* __restrict__ h, const int* __restrict__ eid_s,
    float* __restrict__ agg) {

    __shared__ __align__(16) unsigned short tsT[64][136];  // [edge][filter], stride 272B

    int tid = threadIdx.x;
    int wv = tid >> 6;
    int l15 = tid & 15;
    int q = (tid >> 4) & 3;
    int e_loc = wv * 16 + l15;

    int p = blockIdx.x * 64 + e_loc;       // sorted position, < 1e6
    int eid = eid_s[p];
    int src = edge_index[eid];
    int d   = edge_index[N_EDGES_ + eid];
    int cc  = colors[eid];
    float wwt = edge_weight[eid];
    float cw = 0.5f * (__cosf(wwt * 0.31415926535897932f) + 1.f);   // pi/CUTOFF

    // ---- B-fragments for phase 1, straight from edge_attr (k = q*8+j (+32)) ----
    const float* ear = edge_attr + (size_t)eid * NG;
    float a0[8], a1[8];
    {
        f32x4u u = *(const f32x4u*)(ear + q * 8);
        f32x4u v = *(const f32x4u*)(ear + q * 8 + 4);
        a0[0] = u[0]; a0[1] = u[1]; a0[2] = u[2]; a0[3] = u[3];
        a0[4] = v[0]; a0[5] = v[1]; a0[6] = v[2]; a0[7] = v[3];
    }
#pragma unroll
    for (int j = 0; j < 8; ++j) a1[j] = 0.f;
    if (q < 2) {
        f32x4u u = *(const f32x4u*)(ear + 32 + q * 8);
        f32x4u v = *(const f32x4u*)(ear + 32 + q * 8 + 4);
        a1[0] = u[0]; a1[1] = u[1]; a1[2] = u[2]; a1[3] = u[3];
        a1[4] = v[0]; a1[5] = v[1]; a1[6] = v[2]; a1[7] = v[3];
    } else if (q == 2) {
        f32x2u t = *(const f32x2u*)(ear + 48);
        a1[0] = t[0]; a1[1] = t[1];
    }
    union { s16x8 v; unsigned int u[4]; } bf0, bf1;
#pragma unroll
    for (int j = 0; j < 4; ++j) {
        bf0.u[j] = f2b(a0[2 * j]) | (f2b(a0[2 * j + 1]) << 16);
        bf1.u[j] = f2b(a1[2 * j]) | (f2b(a1[2 * j + 1]) << 16);
    }

    // ---- phase 1: 4 color passes, keep the pass matching this edge's color ----
    f32x4 pre[8];
#pragma unroll
    for (int m = 0; m < 8; ++m) pre[m] = (f32x4)(0.f);
    for (int c = 0; c < NCOL; ++c) {
        const unsigned short* m1p = m1b16 + (size_t)c * NF * 64;
        f32x4 acc[8];
#pragma unroll
        for (int m = 0; m < 8; ++m) acc[m] = (f32x4)(0.f);
#pragma unroll
        for (int m = 0; m < 8; ++m) {
            s16x8 af0 = *(const s16x8*)(m1p + (m * 16 + l15) * 64 + q * 8);
            acc[m] = __builtin_amdgcn_mfma_f32_16x16x32_bf16(af0, bf0.v, acc[m], 0, 0, 0);
            s16x8 af1 = *(const s16x8*)(m1p + (m * 16 + l15) * 64 + q * 8 + 32);
            acc[m] = __builtin_amdgcn_mfma_f32_16x16x32_bf16(af1, bf1.v, acc[m], 0, 0, 0);
        }
        if (cc == c) {
#pragma unroll
            for (int m = 0; m < 8; ++m) pre[m] = acc[m];
        }
    }

    // ---- bias1 + ssp + pack to LDS (intra-wave rows only; no barrier) ----
    {
        const float* b1p = m1bias + cc * NF;
#pragma unroll
        for (int m = 0; m < 8; ++m) {
            int n0 = m * 16 + q * 4;
            f32x4 bv = *(const f32x4*)(b1p + n0);
            float t0 = sspf(pre[m][0] + bv[0]);
            float t1 = sspf(pre[m][1] + bv[1]);
            float t2 = sspf(pre[m][2] + bv[2]);
            float t3 = sspf(pre[m][3] + bv[3]);
            uint2 pk;
            pk.x = f2b(t0) | (f2b(t1) << 16);
            pk.y = f2b(t2) | (f2b(t3) << 16);
            *(uint2*)&tsT[e_loc][n0] = pk;
        }
    }

    // hoist phase-2 B fragments (own row, written by own wave)
    s16x8 tf[4];
#pragma unroll
    for (int ks = 0; ks < 4; ++ks)
        tf[ks] = *(const s16x8*)&tsT[e_loc][q * 8 + 32 * ks];

    // ---- phase 2: 4 color passes, B masked to this pass's color; acc2 sums passes ----
    f32x4 acc2[8];
#pragma unroll
    for (int m = 0; m < 8; ++m) acc2[m] = (f32x4)(0.f);
    for (int c = 0; c < NCOL; ++c) {
        const unsigned short* m2p = m2b16 + (size_t)c * NF * NF;
        s16x8 zero8 = (s16x8)0;
#pragma unroll
        for (int ks = 0; ks < 4; ++ks) {
            s16x8 bf = (cc == c) ? tf[ks] : zero8;
#pragma unroll
            for (int m = 0; m < 8; ++m) {
                s16x8 af = *(const s16x8*)(m2p + (m * 16 + l15) * NF + q * 8 + 32 * ks);
                acc2[m] = __builtin_amdgcn_mfma_f32_16x16x32_bf16(af, bf, acc2[m], 0, 0, 0);
            }
        }
    }

    // ---- epilogue: msg = (u + b2) * cw * h[src]; segmented scan over dst runs ----
    {
        const float* b2p = m2bias + cc * NF;
        const float* hrow = h + (size_t)src * HID;
#pragma unroll
        for (int m = 0; m < 8; ++m) {
            int n0 = m * 16 + q * 4;
            f32x4 bv = *(const f32x4*)(b2p + n0);
            f32x4 hv = *(const f32x4*)(hrow + n0);
#pragma unroll
            for (int j = 0; j < 4; ++j)
                acc2[m][j] = (acc2[m][j] + bv[j]) * cw * hv[j];
        }
    }
#pragma unroll
    for (int dl = 1; dl < 16; dl <<= 1) {
        int dU = __shfl_up(d, dl, 16);
        bool ok = (l15 >= dl) && (dU == d);
#pragma unroll
        for (int m = 0; m < 8; ++m) {
#pragma unroll
            for (int j = 0; j < 4; ++j) {
                float uv = __shfl_up(acc2[m][j], dl, 16);
                if (ok) acc2[m][j] += uv;
            }
        }
    }
    int dD = __shfl_down(d, 1, 16);
    bool tail = (l15 == 15) || (dD != d);
    if (tail) {
        float* arow = agg + (size_t)d * HID;
#pragma unroll
        for (int m = 0; m < 8; ++m) {
            int n0 = m * 16 + q * 4;
            unsafeAtomicAdd(arow + n0 + 0, acc2[m][0]);
            unsafeAtomicAdd(arow + n0 + 1, acc2[m][1]);
            unsafeAtomicAdd(arow + n0 + 2, acc2[m][2]);
            unsafeAtomicAdd(arow + n0 + 3, acc2[m][3]);
        }
    }
}

// ---------------- f32 helpers for lin1 / out ----------------
__device__ __forceinline__ void fma_2x8(float (&acc)[2][8], float2 a, float4 b0, float4 b1) {
    acc[0][0] += a.x * b0.x; acc[0][1] += a.x * b0.y;
    acc[0][2] += a.x * b0.z; acc[0][3] += a.x * b0.w;
    acc[0][4] += a.x * b1.x; acc[0][5] += a.x * b1.y;
    acc[0][6] += a.x * b1.z; acc[0][7] += a.x * b1.w;
    acc[1][0] += a.y * b0.x; acc[1][1] += a.y * b0.y;
    acc[1][2] += a.y * b0.z; acc[1][3] += a.y * b0.w;
    acc[1][4] += a.y * b1.x; acc[1][5] += a.y * b1.y;
    acc[1][6] += a.y * b1.z; acc[1][7] += a.y * b1.w;
}

__device__ __forceinline__ void load_wT32(const float4* __restrict__ w4, int kc,
                                          float (*wT)[132], int tid) {
#pragma unroll
    for (int i = 0; i < 4; ++i) {
        int lin = tid + 256 * i;
        int col = lin >> 3;
        int m = lin & 7;
        float4 v = w4[col * 32 + (kc >> 2) + m];
        wT[4 * m + 0][col] = v.x;
        wT[4 * m + 1][col] = v.y;
        wT[4 * m + 2][col] = v.z;
        wT[4 * m + 3][col] = v.w;
    }
}

__global__ __launch_bounds__(256) void lin1_kernel(const float* __restrict__ x,
                                                   const float* __restrict__ w,
                                                   float* __restrict__ h) {
    __shared__ float xT[HID][36];
    __shared__ float wT[32][132];
    int tid = threadIdx.x;
    int tx = tid & 15, ty = tid >> 4;
    int r0 = blockIdx.x * 32;
    const float4* x4 = (const float4*)x;
#pragma unroll
    for (int i = 0; i < 4; ++i) {
        int lin = tid + 256 * i;
        int r = lin >> 5, m = lin & 31;
        int rr = r0 + r; if (rr > N_NODES_ - 1) rr = N_NODES_ - 1;
        float4 v = x4[rr * 32 + m];
        xT[4 * m + 0][r] = v.x; xT[4 * m + 1][r] = v.y;
        xT[4 * m + 2][r] = v.z; xT[4 * m + 3][r] = v.w;
    }
    float acc[2][8] = {};
    for (int kc = 0; kc < HID; kc += 32) {
        __syncthreads();
        load_wT32((const float4*)w, kc, wT, tid);
        __syncthreads();
#pragma unroll 8
        for (int k2 = 0; k2 < 32; ++k2) {
            float2 a = *(const float2*)&xT[kc + k2][2 * ty];
            float4 b0 = *(const float4*)&wT[k2][8 * tx];
            float4 b1 = *(const float4*)&wT[k2][8 * tx + 4];
            fma_2x8(acc, a, b0, b1);
        }
    }
    float4* h4 = (float4*)h;
#pragma unroll
    for (int i = 0; i < 2; ++i) {
        int row = r0 + 2 * ty + i;
        if (row < N_NODES_) {
            h4[row * 32 + 2 * tx]     = make_float4(acc[i][0], acc[i][1], acc[i][2], acc[i][3]);
            h4[row * 32 + 2 * tx + 1] = make_float4(acc[i][4], acc[i][5], acc[i][6], acc[i][7]);
        }
    }
}

__global__ __launch_bounds__(256) void out_kernel(
    const float* __restrict__ agg,
    const float* __restrict__ w2, const float* __restrict__ b2,
    const float* __restrict__ w3, const float* __restrict__ b3,
    float* __restrict__ out) {
    __shared__ float sT[HID][36];
    __shared__ float wT[32][132];
    int tid = threadIdx.x;
    int tx = tid & 15, ty = tid >> 4;
    int r0 = blockIdx.x * 32;
    const float4* a4 = (const float4*)agg;
#pragma unroll
    for (int i = 0; i < 4; ++i) {
        int lin = tid + 256 * i;
        int r = lin >> 5, m = lin & 31;
        int rr = r0 + r; if (rr > N_NODES_ - 1) rr = N_NODES_ - 1;
        float4 v = a4[rr * 32 + m];
        sT[4 * m + 0][r] = v.x; sT[4 * m + 1][r] = v.y;
        sT[4 * m + 2][r] = v.z; sT[4 * m + 3][r] = v.w;
    }
    float acc[2][8] = {};
    for (int kc = 0; kc < HID; kc += 32) {
        __syncthreads();
        load_wT32((const float4*)w2, kc, wT, tid);
        __syncthreads();
#pragma unroll 8
        for (int k2 = 0; k2 < 32; ++k2) {
            float2 a = *(const float2*)&sT[kc + k2][2 * ty];
            float4 c0 = *(const float4*)&wT[k2][8 * tx];
            float4 c1 = *(const float4*)&wT[k2][8 * tx + 4];
            fma_2x8(acc, a, c0, c1);
        }
    }
    __syncthreads();
#pragma unroll
    for (int j = 0; j < 8; ++j) {
        int col = 8 * tx + j;
        float bbv = b2[col];
        sT[col][2 * ty]     = sspf(acc[0][j] + bbv);
        sT[col][2 * ty + 1] = sspf(acc[1][j] + bbv);
    }
    float acc2[2][8] = {};
    for (int kc = 0; kc < HID; kc += 32) {
        __syncthreads();
        load_wT32((const float4*)w3, kc, wT, tid);
        __syncthreads();
#pragma unroll 8
        for (int k2 = 0; k2 < 32; ++k2) {
            float2 a = *(const float2*)&sT[kc + k2][2 * ty];
            float4 c0 = *(const float4*)&wT[k2][8 * tx];
            float4 c1 = *(const float4*)&wT[k2][8 * tx + 4];
            fma_2x8(acc2, a, c0, c1);
        }
    }
    float4* out4 = (float4*)out;
#pragma unroll
    for (int i = 0; i < 2; ++i) {
        int row = r0 + 2 * ty + i;
        if (row < N_NODES_) {
            out4[row * 32 + 2 * tx] = make_float4(
                acc2[i][0] + b3[8 * tx + 0], acc2[i][1] + b3[8 * tx + 1],
                acc2[i][2] + b3[8 * tx + 2], acc2[i][3] + b3[8 * tx + 3]);
            out4[row * 32 + 2 * tx + 1] = make_float4(
                acc2[i][4] + b3[8 * tx + 4], acc2[i][5] + b3[8 * tx + 5],
                acc2[i][6] + b3[8 * tx + 6], acc2[i][7] + b3[8 * tx + 7]);
        }
    }
}

extern "C" void kernel_launch(void* const* d_in, const int* in_sizes, int n_in,
                              void* d_out, int out_size, void* d_ws, size_t ws_size,
                              hipStream_t stream) {
    const float* x           = (const float*)d_in[0];
    const int*   edge_index  = (const int*)d_in[1];
    const float* edge_weight = (const float*)d_in[2];
    const float* edge_attr   = (const float*)d_in[3];
    const int*   colors      = (const int*)d_in[4];
    const float* m1w         = (const float*)d_in[5];
    const float* m1b         = (const float*)d_in[6];
    const float* m2w         = (const float*)d_in[7];
    const float* m2b         = (const float*)d_in[8];
    const float* lin1w       = (const float*)d_in[9];
    const float* lin2w       = (const float*)d_in[10];
    const float* lin2b       = (const float*)d_in[11];
    const float* linw        = (const float*)d_in[12];
    const float* linb        = (const float*)d_in[13];
    float* out = (float*)d_out;

    // workspace layout (bytes); round 1 proved ws >= 67.2 MB
    char* ws = (char*)d_ws;
    float* h      = (float*)(ws);                         // 25,600,000
    float* agg    = (float*)(ws + 25600000);              // 25,600,000
    int*   eid_s  = (int*)(ws + 51200000);                // 4,000,000
    int*   base   = (int*)(ws + 55200000);                // 200,000 (dst hist/scan/cursor)
    int*   csum   = (int*)(ws + 55400000);                // 320
    int*   cbase  = (int*)(ws + 55400320);                // 320
    unsigned short* m1b16 = (unsigned short*)(ws + 55400704);  // 65,536
    unsigned short* m2b16 = (unsigned short*)(ws + 55466240);  // 131,072

    hipMemsetAsync(agg, 0, (size_t)N_NODES_ * HID * sizeof(float), stream);
    hipMemsetAsync(base, 0, N_NODES_ * sizeof(int), stream);

    hist_kernel<<<(N_EDGES_ + 255) / 256, 256, 0, stream>>>(edge_index, base);
    scan1_kernel<<<NCHUNK, 256, 0, stream>>>(base, csum);
    scan2_kernel<<<1, 64, 0, stream>>>(csum, cbase);
    scan3_kernel<<<NCHUNK, 256, 0, stream>>>(base, cbase);
    scatter_kernel<<<(N_EDGES_ + 255) / 256, 256, 0, stream>>>(edge_index, base, eid_s);
    wconv_kernel<<<(NCOL * NF * 64 + NCOL * NF * NF + 255) / 256, 256, 0, stream>>>(m1w, m2w, m1b16, m2b16);
    lin1_kernel<<<(N_NODES_ + 31) / 32, 256, 0, stream>>>(x, lin1w, h);
    passA_kernel<<<N_EDGES_ / 64, 256, 0, stream>>>(edge_index, edge_weight, edge_attr, colors,
                                                    m1b16, m2b16, m1b, m2b, h, eid_s, agg);
    out_kernel<<<(N_NODES_ + 31) / 32, 256, 0, stream>>>(agg, lin2w, lin2b, linw, linb, out);
}